// Round 2
// baseline (202.036 us; speedup 1.0000x reference)
//
#include <hip/hip_runtime.h>

#define B 8
#define N 2048
#define D 1024
#define C 64           // chunks along i
#define LC (N / C)     // 32
#define M 6            // Taylor terms; |c_j*k_i| <~ 0.2 -> err ~1e-7

// ---------------------------------------------------------------------------
// K1: k[b,n] = dot(x[b,n,:], wk), q[b,n] = dot(x[b,n,:], wq). One wave per row.
__global__ __launch_bounds__(256) void k_proj(const float* __restrict__ x,
                                              const float* __restrict__ wk,
                                              const float* __restrict__ wq,
                                              float* __restrict__ kq) {
    const int wave = threadIdx.x >> 6;
    const int lane = threadIdx.x & 63;
    const int row  = blockIdx.x * 4 + wave;            // [0, B*N)
    const float4* xr  = (const float4*)(x + (size_t)row * D);
    const float4* wk4 = (const float4*)wk;
    const float4* wq4 = (const float4*)wq;
    float ak = 0.f, aq = 0.f;
#pragma unroll
    for (int t = 0; t < (D / 4) / 64; ++t) {           // 4 iterations
        float4 xv = xr[t * 64 + lane];
        float4 kv = wk4[t * 64 + lane];
        float4 qv = wq4[t * 64 + lane];
        ak += xv.x * kv.x + xv.y * kv.y + xv.z * kv.z + xv.w * kv.w;
        aq += xv.x * qv.x + xv.y * qv.y + xv.z * qv.z + xv.w * qv.w;
    }
#pragma unroll
    for (int off = 32; off > 0; off >>= 1) {
        ak += __shfl_down(ak, off, 64);
        aq += __shfl_down(aq, off, 64);
    }
    if (lane == 0) {
        kq[row] = ak;              // k
        kq[B * N + row] = aq;      // q
    }
}

// ---------------------------------------------------------------------------
// K2: chunk partial sums  part[b,c,m,d] = sum_{i in chunk c} k_i^m * f[b,i,d]
//     grid: B*C*2 blocks of 128 threads; each thread owns 4 consecutive d.
__global__ __launch_bounds__(128) void k_partial(const float* __restrict__ kq,
                                                 const float* __restrict__ f,
                                                 float* __restrict__ part) {
    const int dhalf = blockIdx.x & 1;
    const int c     = (blockIdx.x >> 1) & (C - 1);
    const int b     = blockIdx.x >> 7;                 // /(2*C)
    const int d     = dhalf * 512 + threadIdx.x * 4;
    const float*  kb = kq + b * N + c * LC;
    const float4* fb = (const float4*)(f + (size_t)(b * N + c * LC) * D + d);
    float4 s[M];
#pragma unroll
    for (int m = 0; m < M; ++m) s[m] = make_float4(0.f, 0.f, 0.f, 0.f);
#pragma unroll 8
    for (int i = 0; i < LC; ++i) {
        float4 ff = fb[i * (D / 4)];
        float  kk = kb[i];
        float  w  = (kk != 0.0f) ? 1.0f : 0.0f;
        s[0].x += w * ff.x; s[0].y += w * ff.y; s[0].z += w * ff.z; s[0].w += w * ff.w;
        float kp = kk;
#pragma unroll
        for (int m = 1; m < M; ++m) {
            s[m].x += kp * ff.x; s[m].y += kp * ff.y;
            s[m].z += kp * ff.z; s[m].w += kp * ff.w;
            kp *= kk;
        }
    }
    float4* pb = (float4*)(part + ((size_t)(b * C + c) * M) * D + d);
#pragma unroll
    for (int m = 0; m < M; ++m) pb[m * (D / 4)] = s[m];
}

// ---------------------------------------------------------------------------
// K3 (fused): blocks [0,B): exclusive chunk prefix of T_m = sum k^m  (scanT)
//             blocks [B,B+48): exclusive scan of part over c         (scanP)
__global__ __launch_bounds__(256) void k_scan(const float* __restrict__ kq,
                                              float* __restrict__ Tc,
                                              float* __restrict__ part) {
    if (blockIdx.x < B) {
        __shared__ float lds[C][M];
        const int b = blockIdx.x;
        const int c = threadIdx.x;
        if (c < C) {
            float tm[M] = {0.f, 0.f, 0.f, 0.f, 0.f, 0.f};
            const float* kb = kq + b * N + c * LC;
#pragma unroll
            for (int i = 0; i < LC; ++i) {
                float kk = kb[i];
                tm[0] += (kk != 0.0f) ? 1.0f : 0.0f;
                float kp = kk;
#pragma unroll
                for (int m = 1; m < M; ++m) { tm[m] += kp; kp *= kk; }
            }
#pragma unroll
            for (int m = 0; m < M; ++m) lds[c][m] = tm[m];
        }
        __syncthreads();
        if (threadIdx.x == 0) {
            float run[M] = {0.f, 0.f, 0.f, 0.f, 0.f, 0.f};
            for (int c2 = 0; c2 < C; ++c2) {
#pragma unroll
                for (int m = 0; m < M; ++m) {
                    Tc[(b * C + c2) * M + m] = run[m];
                    run[m] += lds[c2][m];
                }
            }
        }
    } else {
        // one thread per (b, m, d4): serial scan over 64 chunks, float4 wide
        const int gid = (blockIdx.x - B) * 256 + threadIdx.x;   // [0, B*M*D/4)
        const int d   = (gid & (D / 4 - 1)) * 4;
        const int m   = (gid >> 8) % M;
        const int b   = gid / (256 * M);
        float4 run = make_float4(0.f, 0.f, 0.f, 0.f);
        for (int c = 0; c < C; ++c) {
            float4* p = (float4*)(part + ((size_t)(b * C + c) * M + m) * D + d);
            float4 v = *p;
            *p = run;
            run.x += v.x; run.y += v.y; run.z += v.z; run.w += v.w;
        }
    }
}

// ---------------------------------------------------------------------------
// K4: main pass — local scan within chunk + Horner polynomial + output.
__global__ __launch_bounds__(128) void k_out(const float* __restrict__ kq,
                                             const float* __restrict__ f,
                                             const float* __restrict__ Tc,
                                             const float* __restrict__ part,
                                             float* __restrict__ out) {
    const int dhalf = blockIdx.x & 1;
    const int c     = (blockIdx.x >> 1) & (C - 1);
    const int b     = blockIdx.x >> 7;
    const int d     = dhalf * 512 + threadIdx.x * 4;

    float4 s[M];
    float  t[M];
    const float4* pb = (const float4*)(part + ((size_t)(b * C + c) * M) * D + d);
#pragma unroll
    for (int m = 0; m < M; ++m) s[m] = pb[m * (D / 4)];
#pragma unroll
    for (int m = 0; m < M; ++m) t[m] = Tc[(b * C + c) * M + m];

    const float*  kb = kq + b * N + c * LC;
    const float*  qb = kq + B * N + b * N + c * LC;
    const float4* fb = (const float4*)(f + (size_t)(b * N + c * LC) * D + d);
    float4*       ob = (float4*)(out + (size_t)(b * N + c * LC) * D + d);

#pragma unroll 4
    for (int i = 0; i < LC; ++i) {
        float4 ff = fb[i * (D / 4)];
        float  kk = kb[i];
        float  qq = qb[i];
        float  w  = (kk != 0.0f) ? 1.0f : 0.0f;
        t[0] += w;
        s[0].x += w * ff.x; s[0].y += w * ff.y; s[0].z += w * ff.z; s[0].w += w * ff.w;
        float kp = kk;
#pragma unroll
        for (int m = 1; m < M; ++m) {
            t[m] += kp;
            s[m].x += kp * ff.x; s[m].y += kp * ff.y;
            s[m].z += kp * ff.z; s[m].w += kp * ff.w;
            kp *= kk;
        }
        // Horner: g_m = c/m; coeff of s[m] becomes c^m/m!
        const float cj = qq * 0.03125f;
        const float g2 = cj * 0.5f;
        const float g3 = cj * (1.0f / 3.0f);
        const float g4 = cj * 0.25f;
        const float g5 = cj * 0.2f;
        float Z = ((((t[5] * g5 + t[4]) * g4 + t[3]) * g3 + t[2]) * g2 + t[1]) * cj + t[0];
        float rz = __builtin_amdgcn_rcpf(Z);
        float4 o;
        o.x = (((((s[5].x * g5 + s[4].x) * g4 + s[3].x) * g3 + s[2].x) * g2 + s[1].x) * cj + s[0].x) * rz;
        o.y = (((((s[5].y * g5 + s[4].y) * g4 + s[3].y) * g3 + s[2].y) * g2 + s[1].y) * cj + s[0].y) * rz;
        o.z = (((((s[5].z * g5 + s[4].z) * g4 + s[3].z) * g3 + s[2].z) * g2 + s[1].z) * cj + s[0].z) * rz;
        o.w = (((((s[5].w * g5 + s[4].w) * g4 + s[3].w) * g3 + s[2].w) * g2 + s[1].w) * cj + s[0].w) * rz;
        ob[i * (D / 4)] = o;
    }
}

// ---------------------------------------------------------------------------
extern "C" void kernel_launch(void* const* d_in, const int* in_sizes, int n_in,
                              void* d_out, int out_size, void* d_ws, size_t ws_size,
                              hipStream_t stream) {
    (void)in_sizes; (void)n_in; (void)out_size; (void)ws_size;
    const float* x  = (const float*)d_in[0];
    const float* f  = (const float*)d_in[1];
    const float* wk = (const float*)d_in[2];
    const float* wq = (const float*)d_in[3];
    float* out = (float*)d_out;
    float* ws  = (float*)d_ws;

    float* kq   = ws;                        // 2*B*N   = 32768 floats
    float* Tc   = ws + 2 * B * N;            // B*C*M   = 3072 floats
    float* part = ws + 2 * B * N + 4096;     // B*C*M*D = 3145728 floats (~12.6 MB)

    hipLaunchKernelGGL(k_proj,    dim3(B * N / 4),          dim3(256), 0, stream, x, wk, wq, kq);
    hipLaunchKernelGGL(k_partial, dim3(B * C * 2),          dim3(128), 0, stream, kq, f, part);
    hipLaunchKernelGGL(k_scan,    dim3(B + B * M * D / 1024), dim3(256), 0, stream, kq, Tc, part);
    hipLaunchKernelGGL(k_out,     dim3(B * C * 2),          dim3(128), 0, stream, kq, f, Tc, part, out);
}

// Round 3
// 195.208 us; speedup vs baseline: 1.0350x; 1.0350x over previous
//
#include <hip/hip_runtime.h>

#define B 8
#define N 2048
#define D 1024
#define C 64           // chunks along i
#define LC (N / C)     // 32
#define M 6            // Taylor terms; |c_j*k_i| <~ 0.2 -> err ~1e-7
#define PB 96          // scanP blocks: B*M*D/4 / 128

// ---------------------------------------------------------------------------
// K1: k[b,n] = dot(x[b,n,:], wk), q[b,n] = dot(x[b,n,:], wq). One wave per row.
__global__ __launch_bounds__(256) void k_proj(const float* __restrict__ x,
                                              const float* __restrict__ wk,
                                              const float* __restrict__ wq,
                                              float* __restrict__ kq) {
    const int wave = threadIdx.x >> 6;
    const int lane = threadIdx.x & 63;
    const int row  = blockIdx.x * 4 + wave;            // [0, B*N)
    const float4* xr  = (const float4*)(x + (size_t)row * D);
    const float4* wk4 = (const float4*)wk;
    const float4* wq4 = (const float4*)wq;
    float ak = 0.f, aq = 0.f;
#pragma unroll
    for (int t = 0; t < (D / 4) / 64; ++t) {           // 4 iterations
        float4 xv = xr[t * 64 + lane];
        float4 kv = wk4[t * 64 + lane];
        float4 qv = wq4[t * 64 + lane];
        ak += xv.x * kv.x + xv.y * kv.y + xv.z * kv.z + xv.w * kv.w;
        aq += xv.x * qv.x + xv.y * qv.y + xv.z * qv.z + xv.w * qv.w;
    }
#pragma unroll
    for (int off = 32; off > 0; off >>= 1) {
        ak += __shfl_down(ak, off, 64);
        aq += __shfl_down(aq, off, 64);
    }
    if (lane == 0) {
        kq[row] = ak;              // k
        kq[B * N + row] = aq;      // q
    }
}

// ---------------------------------------------------------------------------
// K2: chunk partial sums  part[b,c,m,d] = sum_{i in chunk c} k_i^m * f[b,i,d]
//     grid: B*C*2 blocks of 128 threads; each thread owns 4 consecutive d.
__global__ __launch_bounds__(128) void k_partial(const float* __restrict__ kq,
                                                 const float* __restrict__ f,
                                                 float* __restrict__ part) {
    const int dhalf = blockIdx.x & 1;
    const int c     = (blockIdx.x >> 1) & (C - 1);
    const int b     = blockIdx.x >> 7;                 // /(2*C)
    const int d     = dhalf * 512 + threadIdx.x * 4;
    const float*  kb = kq + b * N + c * LC;
    const float4* fb = (const float4*)(f + (size_t)(b * N + c * LC) * D + d);
    float4 s[M];
#pragma unroll
    for (int m = 0; m < M; ++m) s[m] = make_float4(0.f, 0.f, 0.f, 0.f);
#pragma unroll 8
    for (int i = 0; i < LC; ++i) {
        float4 ff = fb[i * (D / 4)];
        float  kk = kb[i];
        float  w  = (kk != 0.0f) ? 1.0f : 0.0f;
        s[0].x += w * ff.x; s[0].y += w * ff.y; s[0].z += w * ff.z; s[0].w += w * ff.w;
        float kp = kk;
#pragma unroll
        for (int m = 1; m < M; ++m) {
            s[m].x += kp * ff.x; s[m].y += kp * ff.y;
            s[m].z += kp * ff.z; s[m].w += kp * ff.w;
            kp *= kk;
        }
    }
    float4* pb = (float4*)(part + ((size_t)(b * C + c) * M) * D + d);
#pragma unroll
    for (int m = 0; m < M; ++m) pb[m * (D / 4)] = s[m];
}

// ---------------------------------------------------------------------------
// K3 (fused): blocks [0,PB): exclusive scan of part over c, 8-deep prefetch.
//             blocks [PB,PB+B): wave-shuffle exclusive scan of T_m (lane = chunk).
__global__ __launch_bounds__(128) void k_scan(const float* __restrict__ kq,
                                              float* __restrict__ Tc,
                                              float* __restrict__ part) {
    if (blockIdx.x < PB) {
        // thread per (b, m, d4), batched loads for latency hiding
        const int gid = blockIdx.x * 128 + threadIdx.x;   // [0, B*M*D/4)
        const int d4  = gid & (D / 4 - 1);                // 0..255
        const int m   = (gid >> 8) % M;
        const int b   = gid / (256 * M);
        float4* p4 = (float4*)part;
        const size_t base = ((size_t)b * C * M + m) * (D / 4) + d4;
        const size_t cs   = (size_t)M * (D / 4);          // stride per chunk, in float4
        float4 run = make_float4(0.f, 0.f, 0.f, 0.f);
#pragma unroll 1
        for (int c0 = 0; c0 < C; c0 += 8) {
            float4 buf[8];
#pragma unroll
            for (int j = 0; j < 8; ++j) buf[j] = p4[base + (size_t)(c0 + j) * cs];
#pragma unroll
            for (int j = 0; j < 8; ++j) {
                float4 v = buf[j];
                p4[base + (size_t)(c0 + j) * cs] = run;
                run.x += v.x; run.y += v.y; run.z += v.z; run.w += v.w;
            }
        }
    } else {
        // scanT: one wave per batch; lane = chunk index
        const int b2   = blockIdx.x - PB;
        const int lane = threadIdx.x;
        if (lane < 64) {
            float tm[M] = {0.f, 0.f, 0.f, 0.f, 0.f, 0.f};
            const float* kb = kq + b2 * N + lane * LC;
#pragma unroll
            for (int i = 0; i < LC; ++i) {
                float kk = kb[i];
                tm[0] += (kk != 0.0f) ? 1.0f : 0.0f;
                float kp = kk;
#pragma unroll
                for (int m = 1; m < M; ++m) { tm[m] += kp; kp *= kk; }
            }
#pragma unroll
            for (int m = 0; m < M; ++m) {
                float v = tm[m];
                const float orig = v;
#pragma unroll
                for (int off = 1; off < 64; off <<= 1) {
                    float nv = __shfl_up(v, off, 64);
                    if (lane >= off) v += nv;
                }
                Tc[(b2 * C + lane) * M + m] = v - orig;   // exclusive prefix
            }
        }
    }
}

// ---------------------------------------------------------------------------
// K4: main pass — local scan within chunk + Horner polynomial + output.
__global__ __launch_bounds__(128) void k_out(const float* __restrict__ kq,
                                             const float* __restrict__ f,
                                             const float* __restrict__ Tc,
                                             const float* __restrict__ part,
                                             float* __restrict__ out) {
    const int dhalf = blockIdx.x & 1;
    const int c     = (blockIdx.x >> 1) & (C - 1);
    const int b     = blockIdx.x >> 7;
    const int d     = dhalf * 512 + threadIdx.x * 4;

    float4 s[M];
    float  t[M];
    const float4* pb = (const float4*)(part + ((size_t)(b * C + c) * M) * D + d);
#pragma unroll
    for (int m = 0; m < M; ++m) s[m] = pb[m * (D / 4)];
#pragma unroll
    for (int m = 0; m < M; ++m) t[m] = Tc[(b * C + c) * M + m];

    const float*  kb = kq + b * N + c * LC;
    const float*  qb = kq + B * N + b * N + c * LC;
    const float4* fb = (const float4*)(f + (size_t)(b * N + c * LC) * D + d);
    float4*       ob = (float4*)(out + (size_t)(b * N + c * LC) * D + d);

#pragma unroll 4
    for (int i = 0; i < LC; ++i) {
        float4 ff = fb[i * (D / 4)];
        float  kk = kb[i];
        float  qq = qb[i];
        float  w  = (kk != 0.0f) ? 1.0f : 0.0f;
        t[0] += w;
        s[0].x += w * ff.x; s[0].y += w * ff.y; s[0].z += w * ff.z; s[0].w += w * ff.w;
        float kp = kk;
#pragma unroll
        for (int m = 1; m < M; ++m) {
            t[m] += kp;
            s[m].x += kp * ff.x; s[m].y += kp * ff.y;
            s[m].z += kp * ff.z; s[m].w += kp * ff.w;
            kp *= kk;
        }
        // Horner: coeff of s[m] is c^m/m!
        const float cj = qq * 0.03125f;
        const float g2 = cj * 0.5f;
        const float g3 = cj * (1.0f / 3.0f);
        const float g4 = cj * 0.25f;
        const float g5 = cj * 0.2f;
        float Z = ((((t[5] * g5 + t[4]) * g4 + t[3]) * g3 + t[2]) * g2 + t[1]) * cj + t[0];
        float rz = __builtin_amdgcn_rcpf(Z);
        float4 o;
        o.x = (((((s[5].x * g5 + s[4].x) * g4 + s[3].x) * g3 + s[2].x) * g2 + s[1].x) * cj + s[0].x) * rz;
        o.y = (((((s[5].y * g5 + s[4].y) * g4 + s[3].y) * g3 + s[2].y) * g2 + s[1].y) * cj + s[0].y) * rz;
        o.z = (((((s[5].z * g5 + s[4].z) * g4 + s[3].z) * g3 + s[2].z) * g2 + s[1].z) * cj + s[0].z) * rz;
        o.w = (((((s[5].w * g5 + s[4].w) * g4 + s[3].w) * g3 + s[2].w) * g2 + s[1].w) * cj + s[0].w) * rz;
        ob[i * (D / 4)] = o;
    }
}

// ---------------------------------------------------------------------------
extern "C" void kernel_launch(void* const* d_in, const int* in_sizes, int n_in,
                              void* d_out, int out_size, void* d_ws, size_t ws_size,
                              hipStream_t stream) {
    (void)in_sizes; (void)n_in; (void)out_size; (void)ws_size;
    const float* x  = (const float*)d_in[0];
    const float* f  = (const float*)d_in[1];
    const float* wk = (const float*)d_in[2];
    const float* wq = (const float*)d_in[3];
    float* out = (float*)d_out;
    float* ws  = (float*)d_ws;

    float* kq   = ws;                        // 2*B*N   = 32768 floats
    float* Tc   = ws + 2 * B * N;            // B*C*M   = 3072 floats
    float* part = ws + 2 * B * N + 4096;     // B*C*M*D = 3145728 floats (~12.6 MB)

    hipLaunchKernelGGL(k_proj,    dim3(B * N / 4),   dim3(256), 0, stream, x, wk, wq, kq);
    hipLaunchKernelGGL(k_partial, dim3(B * C * 2),   dim3(128), 0, stream, kq, f, part);
    hipLaunchKernelGGL(k_scan,    dim3(PB + B),      dim3(128), 0, stream, kq, Tc, part);
    hipLaunchKernelGGL(k_out,     dim3(B * C * 2),   dim3(128), 0, stream, kq, f, Tc, part, out);
}